// Round 1
// baseline (97.942 us; speedup 1.0000x reference)
//
#include <hip/hip_runtime.h>

namespace {

constexpr int kNB  = 256;   // batch
constexpr int kNQ  = 16;    // queries per batch
constexpr int kNK  = 200;   // keys per batch
constexpr int kDK  = 64;    // key/query feature size
constexpr int kNH  = 128;   // hidden
constexpr int kNThr = 640;  // 10 waves
constexpr int kKT  = 80;    // K tile rows held in LDS
constexpr float kNegScale = -1000000000.0f;

struct Smem {
  float kh[kKT][kNH + 4];   // 42240 B, padded row=132 floats: conflict-free float4
  float qh[kNQ][kNH];       // 8192 B (broadcast reads, no pad needed)
  float sc[kNQ][kNK];       // 12800 B
  float wv2[kNH];           // -2*Wv
  float red0;               // bv + sum(Wv)
};                          // total ~63.7 KB (fits 64 KB static LDS)

__launch_bounds__(kNThr, 1)
__global__ void bahdanau_fused(const float* __restrict__ queries,
                               const float* __restrict__ keys,
                               const float* __restrict__ masks,
                               const float* __restrict__ Wq,
                               const float* __restrict__ bq,
                               const float* __restrict__ Wk,
                               const float* __restrict__ bk,
                               const float* __restrict__ Wv,
                               const float* __restrict__ bv,
                               float* __restrict__ out_attn,
                               float* __restrict__ out_w) {
  __shared__ Smem s;
  const int tid  = threadIdx.x;
  const int b    = blockIdx.x;
  const int h    = tid & (kNH - 1);
  const int grp  = __builtin_amdgcn_readfirstlane(tid >> 7);  // 0..4, wave-uniform
  const int lane = tid & 63;
  const int wave = tid >> 6;

  // ---- wv2 = -2*Wv ; red0 = bv + sum(Wv)  (score = red0 + sum(wv2 * rcp(1+e^2x))) ----
  if (tid < kNH) s.wv2[tid] = -2.0f * Wv[tid];
  if (wave == 0) {
    float v = Wv[lane] + Wv[lane + 64];
#pragma unroll
    for (int off = 32; off > 0; off >>= 1) v += __shfl_xor(v, off, 64);
    if (lane == 0) s.red0 = v + bv[0];
  }

  float wcol[kDK];  // weight column for this thread's h
  // ---- qh = 2*(queries @ Wq + bq) into LDS (scaled by 2 so exp arg is 1 add) ----
  {
#pragma unroll
    for (int d = 0; d < kDK; ++d) wcol[d] = Wq[d * kNH + h];
    const float bq_h = bq[h];
    const float* qbase = queries + (size_t)b * kNQ * kDK;
    if (grp < 4) {
#pragma unroll
      for (int i = 0; i < 4; ++i) {
        const int nq = grp * 4 + i;
        const float* qrow = qbase + nq * kDK;  // wave-uniform address
        float a = bq_h;
#pragma unroll
        for (int d = 0; d < kDK; ++d) a = fmaf(qrow[d], wcol[d], a);
        s.qh[nq][h] = 2.0f * a;
      }
    }
  }
  // ---- switch wcol to Wk column ----
#pragma unroll
  for (int d = 0; d < kDK; ++d) wcol[d] = Wk[d * kNH + h];
  const float bk_h = bk[h];
  const float* kbase = keys + (size_t)b * kNK * kDK;

  __syncthreads();
  const float red0 = s.red0;

  // ---- K tiles: proj kh tile -> score pairs ----
  for (int t = 0; t < 3; ++t) {
    const int k0   = t * kKT;
    const int rows = (t == 2) ? (kNK - 2 * kKT) : kKT;  // 80, 80, 40
    const int rpg  = rows / 5;                          // 16, 16, 8 rows per grp

    for (int i = 0; i < rpg; i += 2) {
      const int ka = grp * rpg + i;
      const float* ra = kbase + (size_t)(k0 + ka) * kDK;  // wave-uniform
      const float* rb = ra + kDK;
      float a0 = bk_h, a1 = bk_h;
#pragma unroll
      for (int d = 0; d < kDK; ++d) {
        a0 = fmaf(ra[d], wcol[d], a0);
        a1 = fmaf(rb[d], wcol[d], a1);
      }
      s.kh[ka][h]     = 2.0f * a0;
      s.kh[ka + 1][h] = 2.0f * a1;
    }
    __syncthreads();

    const int npairs = kNQ * rows;  // 1280, 1280, 640 -> exactly 2,2,1 iters/thread
    for (int p = tid; p < npairs; p += kNThr) {
      const int nq = p / rows;
      const int kk = p - nq * rows;
      const float* qrow = s.qh[nq];   // broadcast
      const float* krow = s.kh[kk];   // stride-132 float4: bank-conflict-free
      float ss0 = 0.f, ss1 = 0.f, ss2 = 0.f, ss3 = 0.f;
#pragma unroll
      for (int hh = 0; hh < kNH; hh += 4) {
        const float4 qv = *reinterpret_cast<const float4*>(qrow + hh);
        const float4 kv = *reinterpret_cast<const float4*>(krow + hh);
        const float4 wv = *reinterpret_cast<const float4*>(&s.wv2[hh]);
        // x already scaled by 2: tanh = 1 - 2*rcp(1+exp(x))
        const float e0 = __expf(qv.x + kv.x);
        const float e1 = __expf(qv.y + kv.y);
        const float e2 = __expf(qv.z + kv.z);
        const float e3 = __expf(qv.w + kv.w);
        ss0 = fmaf(wv.x, __builtin_amdgcn_rcpf(1.0f + e0), ss0);
        ss1 = fmaf(wv.y, __builtin_amdgcn_rcpf(1.0f + e1), ss1);
        ss2 = fmaf(wv.z, __builtin_amdgcn_rcpf(1.0f + e2), ss2);
        ss3 = fmaf(wv.w, __builtin_amdgcn_rcpf(1.0f + e3), ss3);
      }
      float sc = red0 + ((ss0 + ss1) + (ss2 + ss3));
      const int kglob = k0 + kk;
      const float mk = masks[(size_t)b * (kNQ * kNK) + nq * kNK + kglob];
      sc = fmaf(mk, kNegScale, sc);
      s.sc[nq][kglob] = sc;
    }
    __syncthreads();
  }

  // ---- softmax over k for each of 16 rows (10 waves; waves 0..5 take 2 rows) ----
#pragma unroll
  for (int rp = 0; rp < 2; ++rp) {
    const int nq = wave + 10 * rp;
    if (nq < kNQ) {
      const float v0 = s.sc[nq][lane];
      const float v1 = s.sc[nq][lane + 64];
      const float v2 = s.sc[nq][lane + 128];
      const bool tail = lane < (kNK - 192);
      const float v3 = tail ? s.sc[nq][lane + 192] : -1e38f;
      float m = fmaxf(fmaxf(v0, v1), fmaxf(v2, v3));
#pragma unroll
      for (int off = 32; off > 0; off >>= 1) m = fmaxf(m, __shfl_xor(m, off, 64));
      const float e0 = __expf(v0 - m);
      const float e1 = __expf(v1 - m);
      const float e2 = __expf(v2 - m);
      const float e3 = tail ? __expf(v3 - m) : 0.f;
      float sum = (e0 + e1) + (e2 + e3);
#pragma unroll
      for (int off = 32; off > 0; off >>= 1) sum += __shfl_xor(sum, off, 64);
      const float rs = __builtin_amdgcn_rcpf(sum);
      float* og = out_w + ((size_t)b * kNQ + nq) * kNK;
      const float w0 = e0 * rs, w1 = e1 * rs, w2 = e2 * rs, w3 = e3 * rs;
      s.sc[nq][lane]       = w0;  og[lane]       = w0;
      s.sc[nq][lane + 64]  = w1;  og[lane + 64]  = w1;
      s.sc[nq][lane + 128] = w2;  og[lane + 128] = w2;
      if (tail) { s.sc[nq][lane + 192] = w3; og[lane + 192] = w3; }
    }
  }
  __syncthreads();

  // ---- attn_out[nq][d] = sum_k w[nq][k] * keys[k][d] ----
  {
    const int g = wave;                 // 0..9
    const bool has2 = (g + 10) < kNQ;   // waves 0..5 also do row g+10
    const int g2 = has2 ? g + 10 : g;
    const float* kb = kbase + lane;     // d = lane
    float a0 = 0.f, a1 = 0.f;
#pragma unroll 8
    for (int k = 0; k < kNK; ++k) {
      const float kv = kb[(size_t)k * kDK];   // coalesced 256B/wave, L2-hot
      a0 = fmaf(s.sc[g][k],  kv, a0);         // broadcast LDS read
      a1 = fmaf(s.sc[g2][k], kv, a1);
    }
    out_attn[((size_t)b * kNQ + g) * kDK + lane] = a0;
    if (has2) out_attn[((size_t)b * kNQ + g + 10) * kDK + lane] = a1;
  }
}

}  // namespace

extern "C" void kernel_launch(void* const* d_in, const int* in_sizes, int n_in,
                              void* d_out, int out_size, void* d_ws, size_t ws_size,
                              hipStream_t stream) {
  const float* queries = (const float*)d_in[0];
  const float* keys    = (const float*)d_in[1];
  const float* masks   = (const float*)d_in[2];
  // d_in[3] = num_neg (unused)
  const float* Wq = (const float*)d_in[4];
  const float* bq = (const float*)d_in[5];
  const float* Wk = (const float*)d_in[6];
  const float* bk = (const float*)d_in[7];
  const float* Wv = (const float*)d_in[8];
  const float* bv = (const float*)d_in[9];

  float* out_attn = (float*)d_out;                       // (B, NQ, 64)
  float* out_w    = out_attn + (size_t)kNB * kNQ * kDK;  // (B, NQ, 200, 1)

  bahdanau_fused<<<kNB, kNThr, 0, stream>>>(queries, keys, masks, Wq, bq, Wk, bk,
                                            Wv, bv, out_attn, out_w);
}

// Round 2
// 57.595 us; speedup vs baseline: 1.7005x; 1.7005x over previous
//
#include <hip/hip_runtime.h>

namespace {

constexpr int kNB  = 256;   // batch
constexpr int kNQ  = 16;    // queries per batch
constexpr int kNK  = 200;   // keys per batch
constexpr int kDK  = 64;    // key/query feature size
constexpr int kNH  = 128;   // hidden
constexpr int kThreads = 1024;  // 16 waves; wave w <-> query row w
constexpr int kTile = 96;       // kh rows per LDS tile (96,96,8)
constexpr int kS    = 132;      // padded kh row stride in floats (4 mod 32 banks)
constexpr float kNeg = -1000000000.0f;
constexpr float kScale2 = 2.8853900817779268f;  // 2*log2(e): exp(2x) = exp2(kScale2*x)

struct Smem {
  float kh[kTile * kS];   // 50688 B   (score-phase K tile)
  float sc[kNQ][kNK];     // 12800 B   (qh staging first, then scores, then weights)
};                        // 63488 B total

__device__ __forceinline__ float exp2_fast(float x) {
#if defined(__has_builtin)
# if __has_builtin(__builtin_amdgcn_exp2f)
  return __builtin_amdgcn_exp2f(x);
# else
  return __expf(x * 0.69314718055994531f);
# endif
#else
  return __expf(x * 0.69314718055994531f);
#endif
}

template <int CTRL>
__device__ __forceinline__ float dpp_add(float v) {
  // v + dpp_move(v): row-local (16-lane) butterfly step on the VALU pipe.
  int sw = __builtin_amdgcn_update_dpp(0, __float_as_int(v), CTRL, 0xF, 0xF, true);
  return v + __int_as_float(sw);
}

__launch_bounds__(kThreads, 1)
__global__ void bahdanau_fused(const float* __restrict__ queries,
                               const float* __restrict__ keys,
                               const float* __restrict__ masks,
                               const float* __restrict__ Wq,
                               const float* __restrict__ bq,
                               const float* __restrict__ Wk,
                               const float* __restrict__ bk,
                               const float* __restrict__ Wv,
                               float* __restrict__ out_attn,
                               float* __restrict__ out_w) {
  __shared__ Smem s;
  const int tid   = threadIdx.x;
  const int b     = blockIdx.x;
  const int lane  = tid & 63;
  const int wave  = __builtin_amdgcn_readfirstlane(tid >> 6);  // 0..15 == nq
  const int j     = lane & 15;        // h-slice index (8 h each)
  const int q16   = lane >> 4;        // k-offset within a score iteration
  const int hbase = 8 * j;
  const int h     = tid & (kNH - 1);  // projection h
  const int kgrp  = __builtin_amdgcn_readfirstlane(tid >> 7);  // 0..7

  float wcol[kDK];

  // ---- qh' = kScale2*(queries @ Wq + bq) staged into sc area as [16][128] ----
  {
#pragma unroll
    for (int d = 0; d < kDK; ++d) wcol[d] = Wq[d * kNH + h];
    const float bqh = bq[h];
    const float* qbase = queries + (size_t)b * kNQ * kDK;
    const float* r0 = qbase + (size_t)kgrp * kDK;        // wave-uniform rows
    const float* r1 = qbase + (size_t)(kgrp + 8) * kDK;
    float a0 = bqh, a1 = bqh;
#pragma unroll
    for (int d = 0; d < kDK; ++d) {
      a0 = fmaf(r0[d], wcol[d], a0);
      a1 = fmaf(r1[d], wcol[d], a1);
    }
    float* qtmp = (float*)s.sc;
    qtmp[kgrp * kNH + h]       = kScale2 * a0;
    qtmp[(kgrp + 8) * kNH + h] = kScale2 * a1;
  }

  // ---- switch wcol to Wk column; per-lane Wv slice ----
#pragma unroll
  for (int d = 0; d < kDK; ++d) wcol[d] = Wk[d * kNH + h];
  const float bkh = bk[h];
  float wv2[8];
#pragma unroll
  for (int m = 0; m < 8; ++m) wv2[m] = -2.0f * Wv[hbase + m];

  __syncthreads();

  // per-lane qh' slice for this wave's query row (registers for the score loop)
  float qreg[8];
  {
    const float* qtmp = (const float*)s.sc;
    const float4 qa = *reinterpret_cast<const float4*>(&qtmp[wave * kNH + hbase]);
    const float4 qb = *reinterpret_cast<const float4*>(&qtmp[wave * kNH + hbase + 4]);
    qreg[0] = qa.x; qreg[1] = qa.y; qreg[2] = qa.z; qreg[3] = qa.w;
    qreg[4] = qb.x; qreg[5] = qb.y; qreg[6] = qb.z; qreg[7] = qb.w;
  }

  const float* kbase = keys + (size_t)b * kNK * kDK;

  // ---- K tiles: project kh' tile -> scores for all 16 query rows ----
  for (int t = 0; t < 3; ++t) {
    const int k0   = t * kTile;
    const int rows = (t < 2) ? kTile : (kNK - 2 * kTile);  // 96, 96, 8
    const int rpg  = rows >> 3;                            // 12, 12, 1

    int i = 0;
    for (; i + 1 < rpg; i += 2) {
      const int rl = kgrp * rpg + i;
      const float* ra = kbase + (size_t)(k0 + rl) * kDK;   // wave-uniform rows
      float a0 = bkh, a1 = bkh;
#pragma unroll
      for (int d = 0; d < kDK; ++d) {
        a0 = fmaf(ra[d], wcol[d], a0);
        a1 = fmaf(ra[d + kDK], wcol[d], a1);
      }
      s.kh[rl * kS + h]       = kScale2 * a0;
      s.kh[(rl + 1) * kS + h] = kScale2 * a1;
    }
    for (; i < rpg; ++i) {
      const int rl = kgrp * rpg + i;
      const float* ra = kbase + (size_t)(k0 + rl) * kDK;
      float a0 = bkh;
#pragma unroll
      for (int d = 0; d < kDK; ++d) a0 = fmaf(ra[d], wcol[d], a0);
      s.kh[rl * kS + h] = kScale2 * a0;
    }
    __syncthreads();

    // score: wave w handles nq=w for all rows of this tile; quarter-wave = one k
#pragma unroll 2
    for (int kk = 0; kk < rows; kk += 4) {
      const float* krow = &s.kh[(size_t)(kk + q16) * kS + hbase];
      const float4 ka = *reinterpret_cast<const float4*>(krow);
      const float4 kb4 = *reinterpret_cast<const float4*>(krow + 4);
      const float e0 = exp2_fast(qreg[0] + ka.x);
      const float e1 = exp2_fast(qreg[1] + ka.y);
      const float e2 = exp2_fast(qreg[2] + ka.z);
      const float e3 = exp2_fast(qreg[3] + ka.w);
      const float e4 = exp2_fast(qreg[4] + kb4.x);
      const float e5 = exp2_fast(qreg[5] + kb4.y);
      const float e6 = exp2_fast(qreg[6] + kb4.z);
      const float e7 = exp2_fast(qreg[7] + kb4.w);
      const float r0 = __builtin_amdgcn_rcpf(1.0f + e0);
      const float r1 = __builtin_amdgcn_rcpf(1.0f + e1);
      const float r2 = __builtin_amdgcn_rcpf(1.0f + e2);
      const float r3 = __builtin_amdgcn_rcpf(1.0f + e3);
      const float r4 = __builtin_amdgcn_rcpf(1.0f + e4);
      const float r5 = __builtin_amdgcn_rcpf(1.0f + e5);
      const float r6 = __builtin_amdgcn_rcpf(1.0f + e6);
      const float r7 = __builtin_amdgcn_rcpf(1.0f + e7);
      float acc0 = wv2[0] * r0;
      acc0 = fmaf(wv2[1], r1, acc0);
      acc0 = fmaf(wv2[2], r2, acc0);
      acc0 = fmaf(wv2[3], r3, acc0);
      float acc1 = wv2[4] * r4;
      acc1 = fmaf(wv2[5], r5, acc1);
      acc1 = fmaf(wv2[6], r6, acc1);
      acc1 = fmaf(wv2[7], r7, acc1);
      float acc = acc0 + acc1;
      // 16-lane butterfly reduce on the VALU pipe (no LDS traffic)
      acc = dpp_add<0xB1>(acc);   // quad_perm [1,0,3,2]  (xor 1)
      acc = dpp_add<0x4E>(acc);   // quad_perm [2,3,0,1]  (xor 2)
      acc = dpp_add<0x141>(acc);  // row_half_mirror      (8-lane fold)
      acc = dpp_add<0x140>(acc);  // row_mirror           (16-lane fold)
      if (j == 0) s.sc[wave][k0 + kk + q16] = acc;
    }
    __syncthreads();
  }

  // ---- softmax over k (wave w owns row w); masks applied here, coalesced ----
  {
    const float* mrow = masks + ((size_t)b * kNQ + wave) * kNK;
    float v0 = fmaf(mrow[lane],       kNeg, s.sc[wave][lane]);
    float v1 = fmaf(mrow[lane + 64],  kNeg, s.sc[wave][lane + 64]);
    float v2 = fmaf(mrow[lane + 128], kNeg, s.sc[wave][lane + 128]);
    const bool tail = lane < (kNK - 192);
    float v3 = tail ? fmaf(mrow[lane + 192], kNeg, s.sc[wave][lane + 192]) : -1e30f;
    float m = fmaxf(fmaxf(v0, v1), fmaxf(v2, v3));
#pragma unroll
    for (int off = 32; off > 0; off >>= 1) m = fmaxf(m, __shfl_xor(m, off, 64));
    const float e0 = __expf(v0 - m);
    const float e1 = __expf(v1 - m);
    const float e2 = __expf(v2 - m);
    const float e3 = tail ? __expf(v3 - m) : 0.f;
    float sum = (e0 + e1) + (e2 + e3);
#pragma unroll
    for (int off = 32; off > 0; off >>= 1) sum += __shfl_xor(sum, off, 64);
    const float rs = __builtin_amdgcn_rcpf(sum);
    float* og = out_w + ((size_t)b * kNQ + wave) * kNK;
    const float w0 = e0 * rs, w1 = e1 * rs, w2 = e2 * rs, w3 = e3 * rs;
    s.sc[wave][lane]       = w0;  og[lane]       = w0;
    s.sc[wave][lane + 64]  = w1;  og[lane + 64]  = w1;
    s.sc[wave][lane + 128] = w2;  og[lane + 128] = w2;
    if (tail) { s.sc[wave][lane + 192] = w3; og[lane + 192] = w3; }
  }
  __syncthreads();

  // ---- attn_out[w][d] = sum_k weight[w][k] * keys[k][d]  (d = lane) ----
  {
    const float* kb = kbase + lane;
    float a0 = 0.f, a1 = 0.f, a2 = 0.f, a3 = 0.f;
#pragma unroll 2
    for (int k = 0; k < kNK; k += 4) {
      const float4 wq = *reinterpret_cast<const float4*>(&s.sc[wave][k]);  // broadcast
      a0 = fmaf(wq.x, kb[(size_t)(k + 0) * kDK], a0);
      a1 = fmaf(wq.y, kb[(size_t)(k + 1) * kDK], a1);
      a2 = fmaf(wq.z, kb[(size_t)(k + 2) * kDK], a2);
      a3 = fmaf(wq.w, kb[(size_t)(k + 3) * kDK], a3);
    }
    out_attn[((size_t)b * kNQ + wave) * kDK + lane] = (a0 + a1) + (a2 + a3);
  }
}

}  // namespace

extern "C" void kernel_launch(void* const* d_in, const int* in_sizes, int n_in,
                              void* d_out, int out_size, void* d_ws, size_t ws_size,
                              hipStream_t stream) {
  const float* queries = (const float*)d_in[0];
  const float* keys    = (const float*)d_in[1];
  const float* masks   = (const float*)d_in[2];
  // d_in[3] = num_neg (unused)
  const float* Wq = (const float*)d_in[4];
  const float* bq = (const float*)d_in[5];
  const float* Wk = (const float*)d_in[6];
  const float* bk = (const float*)d_in[7];
  const float* Wv = (const float*)d_in[8];
  // d_in[9] = bv: softmax-invariant constant, dropped (weights/attn_out unchanged)

  float* out_attn = (float*)d_out;                       // (B, NQ, 64)
  float* out_w    = out_attn + (size_t)kNB * kNQ * kDK;  // (B, NQ, 200, 1)

  bahdanau_fused<<<kNB, kThreads, 0, stream>>>(queries, keys, masks, Wq, bq, Wk, bk,
                                               Wv, out_attn, out_w);
}